// Round 4
// baseline (164.699 us; speedup 1.0000x reference)
//
#include <hip/hip_runtime.h>
#include <hip/hip_bf16.h>

#define BB 16
#define XY 64
#define CC 256
#define PR 66   // padded rows/cols (64 + halo)

typedef __attribute__((ext_vector_type(8))) short short8;
typedef __attribute__((ext_vector_type(4))) float f32x4;
typedef __hip_bfloat16 bf16;

__device__ __forceinline__ void glds16(const void* g, void* l) {
  __builtin_amdgcn_global_load_lds(
      (const __attribute__((address_space(1))) void*)g,
      (__attribute__((address_space(3))) void*)l, 16, 0, 0);
}

// ---------------- Kernel 1: conv1 + BN1 + ReLU -> act2[b][prow 66][cg 32][wp 66][8] bf16
// thread (cg = tid>>3, w8 = tid&7): owns 8 ci (cg*8..+8) at wp = w8+8k.
__global__ __launch_bounds__(256) void k_conv1(
    const float* __restrict__ in,      // (B,64,64)
    const float* __restrict__ w1,      // (C,1,3,3)
    const float* __restrict__ g, const float* __restrict__ bbias,
    const float* __restrict__ m, const float* __restrict__ v,
    bf16* __restrict__ act)
{
  int blk = blockIdx.x;
  int b = blk / PR, prow = blk % PR;
  short8* base = (short8*)(act + (size_t)(b * PR + prow) * 32 * PR * 8);
  int tid = threadIdx.x;
  short8 z8 = {0, 0, 0, 0, 0, 0, 0, 0};
  if (prow == 0 || prow == PR - 1) {            // zero rows (input row -1 / 64)
    for (int i = tid; i < 32 * PR; i += 256) base[i] = z8;
    return;
  }
  __shared__ float inrow[3][PR];
  int h = prow - 1;
  for (int t = tid; t < 3 * PR; t += 256) {
    int r = t / PR, x = t % PR;
    int hr = h - 1 + r, wr = x - 1;
    inrow[r][x] = (hr >= 0 && hr < XY && wr >= 0 && wr < XY)
                      ? in[(b * XY + hr) * XY + wr] : 0.f;
  }
  __syncthreads();
  int cg = tid >> 3, w8 = tid & 7;
  float wr_[8][9], sc[8], tc[8];
#pragma unroll
  for (int u = 0; u < 8; ++u) {
    int c = cg * 8 + u;
#pragma unroll
    for (int t = 0; t < 9; ++t) wr_[u][t] = w1[c * 9 + t];
    float s = g[c] * rsqrtf(v[c] + 1e-5f);
    sc[u] = s; tc[u] = bbias[c] - m[c] * s;
  }
#pragma unroll
  for (int k = 0; k < 9; ++k) {
    int wp = w8 + 8 * k;
    if (wp < PR) {
      short8 outv = z8;
      if (wp != 0 && wp != PR - 1) {
        float o[8];
#pragma unroll
        for (int u = 0; u < 8; ++u) o[u] = 0.f;
#pragma unroll
        for (int dy = 0; dy < 3; ++dy) {
          float i0 = inrow[dy][wp - 1], i1 = inrow[dy][wp], i2 = inrow[dy][wp + 1];
#pragma unroll
          for (int u = 0; u < 8; ++u)
            o[u] += i0 * wr_[u][dy * 3] + i1 * wr_[u][dy * 3 + 1] + i2 * wr_[u][dy * 3 + 2];
        }
#pragma unroll
        for (int u = 0; u < 8; ++u) {
          bf16 hb = __float2bfloat16(fmaxf(fmaf(o[u], sc[u], tc[u]), 0.f));
          outv[u] = *(short*)&hb;
        }
      }
      base[cg * PR + wp] = outv;
    }
  }
}

// ---------------- Kernel 2: w2 -> Wb[(tap*4+c64)][kg 8][co 256][8] bf16, BN2-scaled
// ci = c64*64 + kg*8 + j
__global__ __launch_bounds__(256) void k_wb(
    const float* __restrict__ w2,      // (co, ci, 3, 3)
    const float* __restrict__ g, const float* __restrict__ v,
    bf16* __restrict__ Wb)
{
  int e = blockIdx.x * 256 + threadIdx.x;   // < 589824
  int j   = e & 7;
  int co  = (e >> 3) & 255;
  int kg  = (e >> 11) & 7;
  int c64 = (e >> 14) & 3;
  int tap = e >> 16;
  int ci = c64 * 64 + kg * 8 + j;
  float s = g[co] * rsqrtf(v[co] + 1e-5f);
  Wb[e] = __float2bfloat16(w2[((size_t)co * CC + ci) * 9 + tap] * s);
}

// ---------------- Kernel 3: conv2 via 8-wave 4-phase MFMA pipeline -------------
// BM=256 (4 out rows), BN=256. 512 thr = 8 waves (wm = wid>>2, wn = wid&3).
// Wave tile 128 wp x 64 co: acc[8][4] f32x4. 36 iters (c64 x tap), K=64 each.
// W triple-buffered (staged 2 iters ahead, vmcnt(4) counted); A per c64.
__global__ __launch_bounds__(512, 2) void k_conv2(
    const bf16* __restrict__ act,      // (B,66,32,66,8)
    const bf16* __restrict__ Wb,       // (36,8,256,8)
    const float* __restrict__ in,      // (B,64,64) residual
    const float* __restrict__ g2, const float* __restrict__ b2,
    const float* __restrict__ m2, const float* __restrict__ v2,
    float* __restrict__ out)           // (B,4096,256)
{
  __shared__ alignas(16) bf16 Asm[3168 * 8];     // 50688 B  slot s=(r*8+kg)*66+wp
  __shared__ alignas(16) bf16 Wsm[3][2048 * 8];  // 98304 B  chunk = kg*256+co
  __shared__ float inrow[4][64];

  int gg = blockIdx.x;                  // 256 blocks, XCD swizzle (256%8==0)
  int blk = (gg & 7) * 32 + (gg >> 3);
  int b = blk >> 4, h0 = (blk & 15) << 2;

  int tid = threadIdx.x;
  int lane = tid & 63, wid = tid >> 6;
  int wm = wid >> 2, wn = wid & 3;
  int m = lane & 15, q = lane >> 4;

  f32x4 acc[8][4];
#pragma unroll
  for (int i = 0; i < 8; ++i)
#pragma unroll
    for (int j = 0; j < 4; ++j) acc[i][j] = f32x4{0.f, 0.f, 0.f, 0.f};

  if (tid < 256) inrow[tid >> 6][tid & 63] = in[(b * XY + h0 + (tid >> 6)) * XY + (tid & 63)];
  __syncthreads();

  // ---- staging helpers ----
  auto stageA = [&](int c64) {
#pragma unroll
    for (int rb = 0; rb < 7; ++rb) {
      int sbase = rb * 512 + wid * 64;
      if (sbase < 3168) {                       // wave-uniform
        int s = sbase + lane;
        if (s < 3168) {                          // per-lane (one partial wave)
          int r_row = s / 528;
          int rem = s - r_row * 528;
          int kg = rem / 66;
          int wp = rem - kg * 66;
          size_t gc = ((size_t)(b * PR + h0 + r_row) * 32 + (c64 * 8 + kg)) * PR + wp;
          glds16((const char*)act + gc * 16, (char*)Asm + (size_t)sbase * 16);
        }
      }
    }
  };
  auto stageWhalf = [&](int wblk, int buf, int half) {
    const char* wsrc = (const char*)Wb + (size_t)wblk * 32768;
#pragma unroll
    for (int bt = 0; bt < 2; ++bt) {
      int slotb = (half * 2 + bt) * 512 + wid * 64;
      glds16(wsrc + (size_t)(slotb + lane) * 16,
             (char*)Wsm[buf] + (size_t)slotb * 16);
    }
  };
  auto loadA = [&](short8 af[2][4], int mh, int dy, int dx) {
#pragma unroll
    for (int kk = 0; kk < 2; ++kk)
#pragma unroll
      for (int t = 0; t < 4; ++t) {
        int r = 2 * wm + mh + dy;
        int slot = (r * 8 + kk * 4 + q) * 66 + t * 16 + m + dx;
        af[kk][t] = *(const short8*)(Asm + (size_t)slot * 8);
      }
  };
  auto loadB = [&](short8 bfr[2][2], int buf, int nh) {
#pragma unroll
    for (int kk = 0; kk < 2; ++kk)
#pragma unroll
      for (int t = 0; t < 2; ++t) {
        int slot = (kk * 4 + q) * 256 + wn * 64 + (nh * 2 + t) * 16 + m;
        bfr[kk][t] = *(const short8*)(Wsm[buf] + (size_t)slot * 8);
      }
  };
  auto mfmaQ = [&](short8 af[2][4], short8 bfr[2][2], int mh, int nh) {
    __builtin_amdgcn_s_setprio(1);
#pragma unroll
    for (int kk = 0; kk < 2; ++kk)
#pragma unroll
      for (int t = 0; t < 4; ++t)
#pragma unroll
        for (int u = 0; u < 2; ++u)
          acc[mh * 4 + t][nh * 2 + u] = __builtin_amdgcn_mfma_f32_16x16x32_bf16(
              af[kk][t], bfr[kk][u], acc[mh * 4 + t][nh * 2 + u], 0, 0, 0);
    __builtin_amdgcn_s_setprio(0);
  };

  // ---- prologue: A(c64=0) first, then W(iter0)->buf0, W(iter1)->buf1 ----
  stageA(0);
  stageWhalf(0 * 4 + 0, 0, 0); stageWhalf(0 * 4 + 0, 0, 1);   // iter0 = (tap0,c64_0)
  stageWhalf(1 * 4 + 0, 1, 0); stageWhalf(1 * 4 + 0, 1, 1);   // iter1 = (tap1,c64_0)
  asm volatile("s_waitcnt vmcnt(4)" ::: "memory");  // drain A + W0; keep W1 in flight
  __builtin_amdgcn_s_barrier();

#pragma unroll 1
  for (int c64 = 0; c64 < 4; ++c64) {
#pragma unroll
    for (int tap = 0; tap < 9; ++tap) {
      const int dy = tap / 3, dx = tap % 3;          // compile-time (tap unrolled)
      const int bi = tap % 3;                        // 9%3==0 -> bi resets per c64
      const int sbuf = (tap + 2) % 3;
      const bool doW = (c64 < 3) || (tap < 7);       // iter+2 <= 35
      // wblk for iter+2:
      const int tap2 = (tap + 2) % 9;
      int c64_2 = c64 + ((tap + 2) / 9);
      int wblk2 = tap2 * 4 + c64_2;

      short8 af[2][4], b0[2][2], b1[2][2];
      // ---- P1: A(mh0) + B(nh0) reads; stage W half 0 ----
      loadA(af, 0, dy, dx);
      loadB(b0, bi, 0);
      if (doW) stageWhalf(wblk2, sbuf, 0);
      __builtin_amdgcn_s_barrier();
      asm volatile("s_waitcnt lgkmcnt(0)" ::: "memory");
      __builtin_amdgcn_sched_barrier(0);
      mfmaQ(af, b0, 0, 0);
      __builtin_amdgcn_s_barrier();
      // ---- P2: B(nh1) reads; stage W half 1 ----
      loadB(b1, bi, 1);
      if (doW) stageWhalf(wblk2, sbuf, 1);
      __builtin_amdgcn_s_barrier();
      asm volatile("s_waitcnt lgkmcnt(0)" ::: "memory");
      __builtin_amdgcn_sched_barrier(0);
      mfmaQ(af, b1, 0, 1);
      __builtin_amdgcn_s_barrier();
      // ---- P3: A(mh1) reads ----
      loadA(af, 1, dy, dx);
      __builtin_amdgcn_s_barrier();
      asm volatile("s_waitcnt lgkmcnt(0)" ::: "memory");
      __builtin_amdgcn_sched_barrier(0);
      mfmaQ(af, b1, 1, 1);
      __builtin_amdgcn_s_barrier();
      // ---- P4: (A-reads all done at P3 barrier) optional A-stage; MFMA Q4 ----
      if (tap == 8 && c64 < 3) stageA(c64 + 1);
      __builtin_amdgcn_s_barrier();
      __builtin_amdgcn_sched_barrier(0);
      mfmaQ(af, b0, 1, 0);
      if (tap == 8 || (c64 == 3 && tap >= 7))
        asm volatile("s_waitcnt vmcnt(0)" ::: "memory");   // boundary / tail drain
      else
        asm volatile("s_waitcnt vmcnt(4)" ::: "memory");   // keep iter+2's 4 in flight
      __builtin_amdgcn_s_barrier();
    }
  }

  // ---- epilogue: +bias2, ReLU, +input, ReLU.  C/D: col=lane&15, row=q*4+reg ----
  float t2[4];
#pragma unroll
  for (int nt = 0; nt < 4; ++nt) {
    int co = wn * 64 + nt * 16 + m;
    float s2 = g2[co] * rsqrtf(v2[co] + 1e-5f);
    t2[nt] = b2[co] - m2[co] * s2;
  }
#pragma unroll
  for (int mt = 0; mt < 8; ++mt) {
    int orow2 = 2 * wm + (mt >> 2);
    float* ob = out + ((size_t)(b * XY + h0 + orow2)) * XY * CC;
#pragma unroll
    for (int r = 0; r < 4; ++r) {
      int ocol = (mt & 3) * 16 + q * 4 + r;
      float iv = inrow[orow2][ocol];
#pragma unroll
      for (int nt = 0; nt < 4; ++nt) {
        int co = wn * 64 + nt * 16 + m;
        float val = fmaxf(acc[mt][nt][r] + t2[nt], 0.f);
        ob[(size_t)ocol * CC + co] = fmaxf(iv + val, 0.f);
      }
    }
  }
}

extern "C" void kernel_launch(void* const* d_in, const int* in_sizes, int n_in,
                              void* d_out, int out_size, void* d_ws, size_t ws_size,
                              hipStream_t stream) {
  const float* in_   = (const float*)d_in[0];   // (16,64,64)
  const float* w1    = (const float*)d_in[3];   // (256,1,3,3)
  const float* w2    = (const float*)d_in[4];   // (256,256,3,3)
  const float* bn1_g = (const float*)d_in[5];
  const float* bn1_b = (const float*)d_in[6];
  const float* bn1_m = (const float*)d_in[7];
  const float* bn1_v = (const float*)d_in[8];
  const float* bn2_g = (const float*)d_in[9];
  const float* bn2_b = (const float*)d_in[10];
  const float* bn2_m = (const float*)d_in[11];
  const float* bn2_v = (const float*)d_in[12];
  float* out = (float*)d_out;

  // workspace: act2 (16,66,32,66,8) bf16 = 35.7 MB; Wb (36,2048,8) bf16 = 1.18 MB
  bf16* act = (bf16*)d_ws;
  bf16* Wb  = act + (size_t)BB * PR * 32 * PR * 8;

  k_conv1<<<BB * PR, 256, 0, stream>>>(in_, w1, bn1_g, bn1_b, bn1_m, bn1_v, act);
  k_wb<<<2304, 256, 0, stream>>>(w2, bn2_g, bn2_v, Wb);
  k_conv2<<<256, 512, 0, stream>>>(act, Wb, in_, bn2_g, bn2_b, bn2_m, bn2_v, out);
}

// Round 5
// 116.973 us; speedup vs baseline: 1.4080x; 1.4080x over previous
//
#include <hip/hip_runtime.h>
#include <hip/hip_bf16.h>

#define BB 16
#define XY 64
#define CC 256
#define PR 66   // padded rows/cols (64 + halo)

typedef __attribute__((ext_vector_type(8))) short short8;
typedef __attribute__((ext_vector_type(4))) float f32x4;
typedef __hip_bfloat16 bf16;

__device__ __forceinline__ void glds16(const void* g, void* l) {
  __builtin_amdgcn_global_load_lds(
      (const __attribute__((address_space(1))) void*)g,
      (__attribute__((address_space(3))) void*)l, 16, 0, 0);
}

// ---------------- Kernel 1: conv1 + BN1 + ReLU -> act[b][prow 66][cg 32][wp 66][8] bf16
__global__ __launch_bounds__(256) void k_conv1(
    const float* __restrict__ in,      // (B,64,64)
    const float* __restrict__ w1,      // (C,1,3,3)
    const float* __restrict__ g, const float* __restrict__ bbias,
    const float* __restrict__ m, const float* __restrict__ v,
    bf16* __restrict__ act)
{
  int blk = blockIdx.x;
  int b = blk / PR, prow = blk % PR;
  short8* base = (short8*)(act + (size_t)(b * PR + prow) * 32 * PR * 8);
  int tid = threadIdx.x;
  short8 z8 = {0, 0, 0, 0, 0, 0, 0, 0};
  if (prow == 0 || prow == PR - 1) {
    for (int i = tid; i < 32 * PR; i += 256) base[i] = z8;
    return;
  }
  __shared__ float inrow[3][PR];
  int h = prow - 1;
  for (int t = tid; t < 3 * PR; t += 256) {
    int r = t / PR, x = t % PR;
    int hr = h - 1 + r, wr = x - 1;
    inrow[r][x] = (hr >= 0 && hr < XY && wr >= 0 && wr < XY)
                      ? in[(b * XY + hr) * XY + wr] : 0.f;
  }
  __syncthreads();
  int cg = tid >> 3, w8 = tid & 7;
  float wr_[8][9], sc[8], tc[8];
#pragma unroll
  for (int u = 0; u < 8; ++u) {
    int c = cg * 8 + u;
#pragma unroll
    for (int t = 0; t < 9; ++t) wr_[u][t] = w1[c * 9 + t];
    float s = g[c] * rsqrtf(v[c] + 1e-5f);
    sc[u] = s; tc[u] = bbias[c] - m[c] * s;
  }
#pragma unroll
  for (int k = 0; k < 9; ++k) {
    int wp = w8 + 8 * k;
    if (wp < PR) {
      short8 outv = z8;
      if (wp != 0 && wp != PR - 1) {
        float o[8];
#pragma unroll
        for (int u = 0; u < 8; ++u) o[u] = 0.f;
#pragma unroll
        for (int dy = 0; dy < 3; ++dy) {
          float i0 = inrow[dy][wp - 1], i1 = inrow[dy][wp], i2 = inrow[dy][wp + 1];
#pragma unroll
          for (int u = 0; u < 8; ++u)
            o[u] += i0 * wr_[u][dy * 3] + i1 * wr_[u][dy * 3 + 1] + i2 * wr_[u][dy * 3 + 2];
        }
#pragma unroll
        for (int u = 0; u < 8; ++u) {
          bf16 hb = __float2bfloat16(fmaxf(fmaf(o[u], sc[u], tc[u]), 0.f));
          outv[u] = *(short*)&hb;
        }
      }
      base[cg * PR + wp] = outv;
    }
  }
}

// ---------------- Kernel 2: w2 -> Wb[(tap*4+c64)][P 2048][8] bf16, BN2-scaled ---
// Physical chunk P holds logical chunk L = P ^ (((P>>8)&3)<<1)  (involution).
// Logical L = kg*256 + co; ci = c64*64 + kg*8 + j. Reader XORs (q<<1).
__global__ __launch_bounds__(256) void k_wb(
    const float* __restrict__ w2,      // (co, ci, 3, 3)
    const float* __restrict__ g, const float* __restrict__ v,
    bf16* __restrict__ Wb)
{
  int e = blockIdx.x * 256 + threadIdx.x;   // < 589824
  int j    = e & 7;
  int P    = (e >> 3) & 2047;
  int wblk = e >> 14;
  int tap  = wblk >> 2;
  int c64  = wblk & 3;
  int L = P ^ (((P >> 8) & 3) << 1);
  int kg = L >> 8, co = L & 255;
  int ci = c64 * 64 + kg * 8 + j;
  float s = g[co] * rsqrtf(v[co] + 1e-5f);
  Wb[e] = __float2bfloat16(w2[((size_t)co * CC + ci) * 9 + tap] * s);
}

// ---------------- Kernel 3: conv2 via 8-wave 4-phase MFMA pipeline -------------
// BM=256 (4 out rows x 64 cols), BN=256. 512 thr = 8 waves (wm=wid>>2, wn=wid&3).
// Wave tile: 2 out rows x 64 cols x 64 co -> acc[8][4] f32x4 (AGPR).
// 36 iters (c64 x tap), K=64. W triple-buffered, staged 2 iters ahead, vmcnt(4).
__global__ __launch_bounds__(512, 2) void k_conv2(
    const bf16* __restrict__ act,      // (B,66,32,66,8)
    const bf16* __restrict__ Wb,       // (36,2048,8) swizzled
    const float* __restrict__ in,      // (B,64,64) residual
    const float* __restrict__ g2, const float* __restrict__ b2,
    const float* __restrict__ m2, const float* __restrict__ v2,
    float* __restrict__ out)           // (B,4096,256)
{
  __shared__ alignas(16) bf16 Asm[3168 * 8];     // 50688 B  slot (r*8+kg)*66+wp
  __shared__ alignas(16) bf16 Wsm[3][2048 * 8];  // 98304 B
  __shared__ float inrow[4][64];

  int gg = blockIdx.x;                  // 256 blocks, XCD swizzle (256%8==0)
  int blk = (gg & 7) * 32 + (gg >> 3);
  int b = blk >> 4, h0 = (blk & 15) << 2;

  int tid = threadIdx.x;
  int lane = tid & 63, wid = tid >> 6;
  int wm = wid >> 2, wn = wid & 3;
  int m = lane & 15, q = lane >> 4;

  f32x4 acc[8][4];
#pragma unroll
  for (int i = 0; i < 8; ++i)
#pragma unroll
    for (int j = 0; j < 4; ++j) acc[i][j] = f32x4{0.f, 0.f, 0.f, 0.f};

  if (tid < 256) inrow[tid >> 6][tid & 63] = in[(b * XY + h0 + (tid >> 6)) * XY + (tid & 63)];
  __syncthreads();

  auto stageA = [&](int c64) {
#pragma unroll
    for (int rb = 0; rb < 7; ++rb) {
      int sbase = rb * 512 + wid * 64;
      if (sbase < 3168) {
        int s = sbase + lane;
        if (s < 3168) {
          int r_row = s / 528;
          int rem = s - r_row * 528;
          int kg = rem / 66;
          int wp = rem - kg * 66;
          size_t gc = ((size_t)(b * PR + h0 + r_row) * 32 + (c64 * 8 + kg)) * PR + wp;
          glds16((const char*)act + gc * 16, (char*)Asm + (size_t)sbase * 16);
        }
      }
    }
  };
  auto stageWhalf = [&](int wblk, int buf, int half) {
    const char* wsrc = (const char*)Wb + (size_t)wblk * 32768;
#pragma unroll
    for (int bt = 0; bt < 2; ++bt) {
      int slotb = (half * 2 + bt) * 512 + wid * 64;
      glds16(wsrc + (size_t)(slotb + lane) * 16,
             (char*)Wsm[buf] + (size_t)slotb * 16);
    }
  };

  // ---- prologue: A(c64=0), then W(iter0)->buf0, W(iter1)->buf1 ----
  stageA(0);
  stageWhalf(0, 0, 0); stageWhalf(0, 0, 1);       // iter0 = (tap0,c64_0), wblk 0
  stageWhalf(4, 1, 0); stageWhalf(4, 1, 1);       // iter1 = (tap1,c64_0), wblk 4
  asm volatile("s_waitcnt vmcnt(4)" ::: "memory");
  __builtin_amdgcn_s_barrier();

#pragma unroll 1
  for (int c64 = 0; c64 < 4; ++c64) {
#pragma unroll
    for (int tap = 0; tap < 9; ++tap) {
      const int dy = tap / 3, dx = tap % 3;
      const int bi = tap % 3;                      // buffer of this iter
      const int sbuf = (tap + 2) % 3;              // stage target (iter+2)
      const bool doW = (c64 < 3) || (tap < 7);
      const int tap2 = (tap + 2) % 9;
      const int c64_2 = c64 + ((tap + 2) / 9);     // runtime scalar, fine

      short8 af[2][4], bA[2][2], bB[2][2];         // constant-indexed only

      // ---- P1: A(mh=0) + B(nh=0) reads; stage W half0 ----
#pragma unroll
      for (int kk = 0; kk < 2; ++kk)
#pragma unroll
        for (int t = 0; t < 4; ++t)
          af[kk][t] = *(const short8*)(Asm +
              (size_t)((((2 * wm + dy) * 8 + kk * 4 + q) * 66) + t * 16 + m + dx) * 8);
#pragma unroll
      for (int kk = 0; kk < 2; ++kk)
#pragma unroll
        for (int u = 0; u < 2; ++u) {
          int L = (kk * 4 + q) * 256 + wn * 64 + u * 16 + m;
          bA[kk][u] = *(const short8*)(Wsm[bi] + (size_t)(L ^ (q << 1)) * 8);
        }
      if (doW) stageWhalf(tap2 * 4 + c64_2, sbuf, 0);
      __builtin_amdgcn_s_barrier();
      asm volatile("s_waitcnt lgkmcnt(0)" ::: "memory");
      __builtin_amdgcn_sched_barrier(0);
      __builtin_amdgcn_s_setprio(1);
#pragma unroll
      for (int kk = 0; kk < 2; ++kk)
#pragma unroll
        for (int t = 0; t < 4; ++t)
#pragma unroll
          for (int u = 0; u < 2; ++u)
            acc[t][u] = __builtin_amdgcn_mfma_f32_16x16x32_bf16(
                af[kk][t], bA[kk][u], acc[t][u], 0, 0, 0);
      __builtin_amdgcn_s_setprio(0);
      __builtin_amdgcn_s_barrier();

      // ---- P2: B(nh=1) reads; stage W half1 ----
#pragma unroll
      for (int kk = 0; kk < 2; ++kk)
#pragma unroll
        for (int u = 0; u < 2; ++u) {
          int L = (kk * 4 + q) * 256 + wn * 64 + (2 + u) * 16 + m;
          bB[kk][u] = *(const short8*)(Wsm[bi] + (size_t)(L ^ (q << 1)) * 8);
        }
      if (doW) stageWhalf(tap2 * 4 + c64_2, sbuf, 1);
      __builtin_amdgcn_s_barrier();
      asm volatile("s_waitcnt lgkmcnt(0)" ::: "memory");
      __builtin_amdgcn_sched_barrier(0);
      __builtin_amdgcn_s_setprio(1);
#pragma unroll
      for (int kk = 0; kk < 2; ++kk)
#pragma unroll
        for (int t = 0; t < 4; ++t)
#pragma unroll
          for (int u = 0; u < 2; ++u)
            acc[t][2 + u] = __builtin_amdgcn_mfma_f32_16x16x32_bf16(
                af[kk][t], bB[kk][u], acc[t][2 + u], 0, 0, 0);
      __builtin_amdgcn_s_setprio(0);
      __builtin_amdgcn_s_barrier();

      // ---- P3: A(mh=1) reads ----
#pragma unroll
      for (int kk = 0; kk < 2; ++kk)
#pragma unroll
        for (int t = 0; t < 4; ++t)
          af[kk][t] = *(const short8*)(Asm +
              (size_t)((((2 * wm + 1 + dy) * 8 + kk * 4 + q) * 66) + t * 16 + m + dx) * 8);
      __builtin_amdgcn_s_barrier();
      asm volatile("s_waitcnt lgkmcnt(0)" ::: "memory");
      __builtin_amdgcn_sched_barrier(0);
      __builtin_amdgcn_s_setprio(1);
#pragma unroll
      for (int kk = 0; kk < 2; ++kk)
#pragma unroll
        for (int t = 0; t < 4; ++t)
#pragma unroll
          for (int u = 0; u < 2; ++u)
            acc[4 + t][2 + u] = __builtin_amdgcn_mfma_f32_16x16x32_bf16(
                af[kk][t], bB[kk][u], acc[4 + t][2 + u], 0, 0, 0);
      __builtin_amdgcn_s_setprio(0);
      __builtin_amdgcn_s_barrier();

      // ---- P4: optional A-stage for next c64; MFMA Q(1,0); counted vmcnt ----
      if (tap == 8 && c64 < 3) stageA(c64 + 1);
      __builtin_amdgcn_s_setprio(1);
#pragma unroll
      for (int kk = 0; kk < 2; ++kk)
#pragma unroll
        for (int t = 0; t < 4; ++t)
#pragma unroll
          for (int u = 0; u < 2; ++u)
            acc[4 + t][u] = __builtin_amdgcn_mfma_f32_16x16x32_bf16(
                af[kk][t], bA[kk][u], acc[4 + t][u], 0, 0, 0);
      __builtin_amdgcn_s_setprio(0);
      if (tap == 8 || (c64 == 3 && tap >= 7))
        asm volatile("s_waitcnt vmcnt(0)" ::: "memory");
      else
        asm volatile("s_waitcnt vmcnt(4)" ::: "memory");
      __builtin_amdgcn_s_barrier();
    }
  }

  // ---- epilogue: +bias2, ReLU, +input, ReLU.  C/D: col=lane&15, row=q*4+reg ----
  float t2[4];
#pragma unroll
  for (int nt = 0; nt < 4; ++nt) {
    int co = wn * 64 + nt * 16 + m;
    float s2 = g2[co] * rsqrtf(v2[co] + 1e-5f);
    t2[nt] = b2[co] - m2[co] * s2;
  }
#pragma unroll
  for (int mt = 0; mt < 8; ++mt) {
    int orow2 = 2 * wm + (mt >> 2);
    float* ob = out + ((size_t)(b * XY + h0 + orow2)) * XY * CC;
#pragma unroll
    for (int r = 0; r < 4; ++r) {
      int ocol = (mt & 3) * 16 + q * 4 + r;
      float iv = inrow[orow2][ocol];
#pragma unroll
      for (int nt = 0; nt < 4; ++nt) {
        int co = wn * 64 + nt * 16 + m;
        float val = fmaxf(acc[mt][nt][r] + t2[nt], 0.f);
        ob[(size_t)ocol * CC + co] = fmaxf(iv + val, 0.f);
      }
    }
  }
}

extern "C" void kernel_launch(void* const* d_in, const int* in_sizes, int n_in,
                              void* d_out, int out_size, void* d_ws, size_t ws_size,
                              hipStream_t stream) {
  const float* in_   = (const float*)d_in[0];   // (16,64,64)
  const float* w1    = (const float*)d_in[3];   // (256,1,3,3)
  const float* w2    = (const float*)d_in[4];   // (256,256,3,3)
  const float* bn1_g = (const float*)d_in[5];
  const float* bn1_b = (const float*)d_in[6];
  const float* bn1_m = (const float*)d_in[7];
  const float* bn1_v = (const float*)d_in[8];
  const float* bn2_g = (const float*)d_in[9];
  const float* bn2_b = (const float*)d_in[10];
  const float* bn2_m = (const float*)d_in[11];
  const float* bn2_v = (const float*)d_in[12];
  float* out = (float*)d_out;

  bf16* act = (bf16*)d_ws;                         // (16,66,32,66,8) bf16 = 35.7 MB
  bf16* Wb  = act + (size_t)BB * PR * 32 * PR * 8; // (36,2048,8) bf16 = 1.18 MB

  k_conv1<<<BB * PR, 256, 0, stream>>>(in_, w1, bn1_g, bn1_b, bn1_m, bn1_v, act);
  k_wb<<<2304, 256, 0, stream>>>(w2, bn2_g, bn2_v, Wb);
  k_conv2<<<256, 512, 0, stream>>>(act, Wb, in_, bn2_g, bn2_b, bn2_m, bn2_v, out);
}

// Round 6
// 109.811 us; speedup vs baseline: 1.4998x; 1.0652x over previous
//
#include <hip/hip_runtime.h>
#include <hip/hip_bf16.h>

#define BB 16
#define XY 64
#define CC 256
#define PR 66   // padded rows/cols (64 + halo)

typedef __attribute__((ext_vector_type(8))) short short8;
typedef __attribute__((ext_vector_type(4))) float f32x4;
typedef __hip_bfloat16 bf16;

__device__ __forceinline__ void glds16(const void* g, void* l) {
  __builtin_amdgcn_global_load_lds(
      (const __attribute__((address_space(1))) void*)g,
      (__attribute__((address_space(3))) void*)l, 16, 0, 0);
}

// ---------------- Kernel 1: conv1 + BN1 + ReLU -> act[b][prow 66][cg 32][wp 66][8] bf16
__global__ __launch_bounds__(256) void k_conv1(
    const float* __restrict__ in,      // (B,64,64)
    const float* __restrict__ w1,      // (C,1,3,3)
    const float* __restrict__ g, const float* __restrict__ bbias,
    const float* __restrict__ m, const float* __restrict__ v,
    bf16* __restrict__ act)
{
  int blk = blockIdx.x;
  int b = blk / PR, prow = blk % PR;
  short8* base = (short8*)(act + (size_t)(b * PR + prow) * 32 * PR * 8);
  int tid = threadIdx.x;
  short8 z8 = {0, 0, 0, 0, 0, 0, 0, 0};
  if (prow == 0 || prow == PR - 1) {
    for (int i = tid; i < 32 * PR; i += 256) base[i] = z8;
    return;
  }
  __shared__ float inrow[3][PR];
  int h = prow - 1;
  for (int t = tid; t < 3 * PR; t += 256) {
    int r = t / PR, x = t % PR;
    int hr = h - 1 + r, wr = x - 1;
    inrow[r][x] = (hr >= 0 && hr < XY && wr >= 0 && wr < XY)
                      ? in[(b * XY + hr) * XY + wr] : 0.f;
  }
  __syncthreads();
  int cg = tid >> 3, w8 = tid & 7;
  float wr_[8][9], sc[8], tc[8];
#pragma unroll
  for (int u = 0; u < 8; ++u) {
    int c = cg * 8 + u;
#pragma unroll
    for (int t = 0; t < 9; ++t) wr_[u][t] = w1[c * 9 + t];
    float s = g[c] * rsqrtf(v[c] + 1e-5f);
    sc[u] = s; tc[u] = bbias[c] - m[c] * s;
  }
#pragma unroll
  for (int k = 0; k < 9; ++k) {
    int wp = w8 + 8 * k;
    if (wp < PR) {
      short8 outv = z8;
      if (wp != 0 && wp != PR - 1) {
        float o[8];
#pragma unroll
        for (int u = 0; u < 8; ++u) o[u] = 0.f;
#pragma unroll
        for (int dy = 0; dy < 3; ++dy) {
          float i0 = inrow[dy][wp - 1], i1 = inrow[dy][wp], i2 = inrow[dy][wp + 1];
#pragma unroll
          for (int u = 0; u < 8; ++u)
            o[u] += i0 * wr_[u][dy * 3] + i1 * wr_[u][dy * 3 + 1] + i2 * wr_[u][dy * 3 + 2];
        }
#pragma unroll
        for (int u = 0; u < 8; ++u) {
          bf16 hb = __float2bfloat16(fmaxf(fmaf(o[u], sc[u], tc[u]), 0.f));
          outv[u] = *(short*)&hb;
        }
      }
      base[cg * PR + wp] = outv;
    }
  }
}

// ---------------- Kernel 2: w2 -> Wb[(tap*4+c64)][P 2048][8] bf16, BN2-scaled ---
// Physical chunk P holds logical chunk L = P ^ (((P>>8)&3)<<1)  (involution).
// Logical L = kg*256 + co; ci = c64*64 + kg*8 + j. Reader XORs (q<<1).
__global__ __launch_bounds__(256) void k_wb(
    const float* __restrict__ w2,      // (co, ci, 3, 3)
    const float* __restrict__ g, const float* __restrict__ v,
    bf16* __restrict__ Wb)
{
  int e = blockIdx.x * 256 + threadIdx.x;   // < 589824
  int j    = e & 7;
  int P    = (e >> 3) & 2047;
  int wblk = e >> 14;
  int tap  = wblk >> 2;
  int c64  = wblk & 3;
  int L = P ^ (((P >> 8) & 3) << 1);
  int kg = L >> 8, co = L & 255;
  int ci = c64 * 64 + kg * 8 + j;
  float s = g[co] * rsqrtf(v[co] + 1e-5f);
  Wb[e] = __float2bfloat16(w2[((size_t)co * CC + ci) * 9 + tap] * s);
}

// ---------------- Kernel 3: conv2 via 8-wave 4-phase MFMA pipeline -------------
// BM=256 (4 out rows x 64 cols), BN=256. 512 thr = 8 waves (wm=wid>>2, wn=wid&3).
// Wave tile: 2 out rows x 64 cols x 64 co -> acc[8][4] f32x4.
// 36 iters (c64 x tap), K=64. W triple-buffered, staged 2 iters ahead, vmcnt(4).
// Compact body (tap loop NOT unrolled); no asm lgkm / sched_barrier pinning.
__global__ __launch_bounds__(512, 2) void k_conv2(
    const bf16* __restrict__ act,      // (B,66,32,66,8)
    const bf16* __restrict__ Wb,       // (36,2048,8) swizzled
    const float* __restrict__ in,      // (B,64,64) residual
    const float* __restrict__ g2, const float* __restrict__ b2,
    const float* __restrict__ m2, const float* __restrict__ v2,
    float* __restrict__ out)           // (B,4096,256)
{
  __shared__ alignas(16) bf16 Asm[3168 * 8];     // 50688 B  slot (r*8+kg)*66+wp
  __shared__ alignas(16) bf16 Wsm[3][2048 * 8];  // 98304 B
  __shared__ float inrow[4][64];

  int gg = blockIdx.x;                  // 256 blocks, XCD swizzle (256%8==0)
  int blk = (gg & 7) * 32 + (gg >> 3);
  int b = blk >> 4, h0 = (blk & 15) << 2;

  int tid = threadIdx.x;
  int lane = tid & 63, wid = tid >> 6;
  int wm = wid >> 2, wn = wid & 3;
  int m = lane & 15, q = lane >> 4;

  f32x4 acc[8][4];
#pragma unroll
  for (int i = 0; i < 8; ++i)
#pragma unroll
    for (int j = 0; j < 4; ++j) acc[i][j] = f32x4{0.f, 0.f, 0.f, 0.f};

  if (tid < 256) inrow[tid >> 6][tid & 63] = in[(b * XY + h0 + (tid >> 6)) * XY + (tid & 63)];
  __syncthreads();   // drains inrow vm+lgkm -> uniform vmcnt from here on

  // each wave issues EXACTLY 7 A-glds (overlapping coverage; double-writes benign)
  auto stageA = [&](int cn) {
    int basep = wid * 396;
#pragma unroll
    for (int k = 0; k < 7; ++k) {
      int sb = basep + k * 64;
      int s = sb + lane;
      if (s < 3168) {
        int r_row = s / 528;
        int rem = s - r_row * 528;
        int kg = rem / 66;
        int wp = rem - kg * 66;
        size_t gc = ((size_t)(b * PR + h0 + r_row) * 32 + (cn * 8 + kg)) * PR + wp;
        glds16((const char*)act + gc * 16, (char*)Asm + (size_t)sb * 16);
      }
    }
  };
  auto stageWhalf = [&](int wblk, int buf, int half) {
    const char* wsrc = (const char*)Wb + (size_t)wblk * 32768;
#pragma unroll
    for (int bt = 0; bt < 2; ++bt) {
      int slotb = (half * 2 + bt) * 512 + wid * 64;
      glds16(wsrc + (size_t)(slotb + lane) * 16,
             (char*)Wsm[buf] + (size_t)slotb * 16);
    }
  };

  // ---- prologue: A(c64=0), then W(iter0)->buf0, W(iter1)->buf1 ----
  stageA(0);
  stageWhalf(0, 0, 0); stageWhalf(0, 0, 1);       // iter0 (tap0,c64_0) -> buf0
  stageWhalf(4, 1, 0); stageWhalf(4, 1, 1);       // iter1 (tap1,c64_0) -> buf1
  asm volatile("s_waitcnt vmcnt(4)" ::: "memory"); // drain A+W0, keep W1 in flight
  __builtin_amdgcn_s_barrier();

#pragma unroll 1
  for (int c64 = 0; c64 < 4; ++c64) {
#pragma unroll 1
    for (int tap = 0; tap < 9; ++tap) {
      int dy = tap / 3, dx = tap - dy * 3;     // note: buffer bi == tap%3 == dx
      int sbuf = dx + 2; if (sbuf >= 3) sbuf -= 3;
      bool doW = (c64 < 3) || (tap < 7);
      int tap2 = tap + 2, c2 = c64;
      if (tap2 >= 9) { tap2 -= 9; ++c2; }
      int wblk2 = tap2 * 4 + c2;
      const bf16* wbuf = &Wsm[0][0] + (size_t)dx * (2048 * 8);

      int arow = ((2 * wm + dy) * 8 + q) * 66 + m + dx;   // chunk idx, mh=0
      short8 a0[2][4], a1[2][4], bA[2][2], bB[2][2];

      // ---- P1: A(mh0) + B(nh0) reads; stage W half0; MFMA Q(0,0) ----
#pragma unroll
      for (int kk = 0; kk < 2; ++kk)
#pragma unroll
        for (int t = 0; t < 4; ++t)
          a0[kk][t] = *(const short8*)(Asm + (size_t)(arow + kk * 264 + t * 16) * 8);
#pragma unroll
      for (int kk = 0; kk < 2; ++kk)
#pragma unroll
        for (int u = 0; u < 2; ++u) {
          int L = (kk * 4 + q) * 256 + wn * 64 + u * 16 + m;
          bA[kk][u] = *(const short8*)(wbuf + (size_t)(L ^ (q << 1)) * 8);
        }
      if (doW) stageWhalf(wblk2, sbuf, 0);
      __builtin_amdgcn_s_barrier();
      __builtin_amdgcn_s_setprio(1);
#pragma unroll
      for (int kk = 0; kk < 2; ++kk)
#pragma unroll
        for (int t = 0; t < 4; ++t)
#pragma unroll
          for (int u = 0; u < 2; ++u)
            acc[t][u] = __builtin_amdgcn_mfma_f32_16x16x32_bf16(
                a0[kk][t], bA[kk][u], acc[t][u], 0, 0, 0);
      __builtin_amdgcn_s_setprio(0);
      __builtin_amdgcn_s_barrier();

      // ---- P2: B(nh1) reads; stage W half1; MFMA Q(0,1) ----
#pragma unroll
      for (int kk = 0; kk < 2; ++kk)
#pragma unroll
        for (int u = 0; u < 2; ++u) {
          int L = (kk * 4 + q) * 256 + wn * 64 + (2 + u) * 16 + m;
          bB[kk][u] = *(const short8*)(wbuf + (size_t)(L ^ (q << 1)) * 8);
        }
      if (doW) stageWhalf(wblk2, sbuf, 1);
      __builtin_amdgcn_s_barrier();
      __builtin_amdgcn_s_setprio(1);
#pragma unroll
      for (int kk = 0; kk < 2; ++kk)
#pragma unroll
        for (int t = 0; t < 4; ++t)
#pragma unroll
          for (int u = 0; u < 2; ++u)
            acc[t][2 + u] = __builtin_amdgcn_mfma_f32_16x16x32_bf16(
                a0[kk][t], bB[kk][u], acc[t][2 + u], 0, 0, 0);
      __builtin_amdgcn_s_setprio(0);
      __builtin_amdgcn_s_barrier();

      // ---- P3: A(mh1) reads; MFMA Q(1,1) ----
#pragma unroll
      for (int kk = 0; kk < 2; ++kk)
#pragma unroll
        for (int t = 0; t < 4; ++t)
          a1[kk][t] = *(const short8*)(Asm + (size_t)(arow + 528 + kk * 264 + t * 16) * 8);
      __builtin_amdgcn_s_barrier();
      __builtin_amdgcn_s_setprio(1);
#pragma unroll
      for (int kk = 0; kk < 2; ++kk)
#pragma unroll
        for (int t = 0; t < 4; ++t)
#pragma unroll
          for (int u = 0; u < 2; ++u)
            acc[4 + t][2 + u] = __builtin_amdgcn_mfma_f32_16x16x32_bf16(
                a1[kk][t], bB[kk][u], acc[4 + t][2 + u], 0, 0, 0);
      __builtin_amdgcn_s_setprio(0);
      __builtin_amdgcn_s_barrier();

      // ---- P4: A-burst for next c64 (tap 8); MFMA Q(1,0); counted vmcnt ----
      if (tap == 8 && c64 < 3) stageA(c64 + 1);
      __builtin_amdgcn_s_setprio(1);
#pragma unroll
      for (int kk = 0; kk < 2; ++kk)
#pragma unroll
        for (int t = 0; t < 4; ++t)
#pragma unroll
          for (int u = 0; u < 2; ++u)
            acc[4 + t][u] = __builtin_amdgcn_mfma_f32_16x16x32_bf16(
                a1[kk][t], bA[kk][u], acc[4 + t][u], 0, 0, 0);
      __builtin_amdgcn_s_setprio(0);
      if (tap == 8 || (c64 == 3 && tap == 7))
        asm volatile("s_waitcnt vmcnt(0)" ::: "memory");   // c64 boundary / tail
      else
        asm volatile("s_waitcnt vmcnt(4)" ::: "memory");   // keep iter+2's W in flight
      __builtin_amdgcn_s_barrier();
    }
  }

  // ---- epilogue: +bias2, ReLU, +input, ReLU.  C/D: col=lane&15, row=q*4+reg ----
  float t2[4];
#pragma unroll
  for (int nt = 0; nt < 4; ++nt) {
    int co = wn * 64 + nt * 16 + m;
    float s2 = g2[co] * rsqrtf(v2[co] + 1e-5f);
    t2[nt] = b2[co] - m2[co] * s2;
  }
#pragma unroll
  for (int mt = 0; mt < 8; ++mt) {
    int orow2 = 2 * wm + (mt >> 2);
    float* ob = out + ((size_t)(b * XY + h0 + orow2)) * XY * CC;
#pragma unroll
    for (int r = 0; r < 4; ++r) {
      int ocol = (mt & 3) * 16 + q * 4 + r;
      float iv = inrow[orow2][ocol];
#pragma unroll
      for (int nt = 0; nt < 4; ++nt) {
        int co = wn * 64 + nt * 16 + m;
        float val = fmaxf(acc[mt][nt][r] + t2[nt], 0.f);
        ob[(size_t)ocol * CC + co] = fmaxf(iv + val, 0.f);
      }
    }
  }
}

extern "C" void kernel_launch(void* const* d_in, const int* in_sizes, int n_in,
                              void* d_out, int out_size, void* d_ws, size_t ws_size,
                              hipStream_t stream) {
  const float* in_   = (const float*)d_in[0];   // (16,64,64)
  const float* w1    = (const float*)d_in[3];   // (256,1,3,3)
  const float* w2    = (const float*)d_in[4];   // (256,256,3,3)
  const float* bn1_g = (const float*)d_in[5];
  const float* bn1_b = (const float*)d_in[6];
  const float* bn1_m = (const float*)d_in[7];
  const float* bn1_v = (const float*)d_in[8];
  const float* bn2_g = (const float*)d_in[9];
  const float* bn2_b = (const float*)d_in[10];
  const float* bn2_m = (const float*)d_in[11];
  const float* bn2_v = (const float*)d_in[12];
  float* out = (float*)d_out;

  bf16* act = (bf16*)d_ws;                         // (16,66,32,66,8) bf16 = 35.7 MB
  bf16* Wb  = act + (size_t)BB * PR * 32 * PR * 8; // (36,2048,8) bf16 = 1.18 MB

  k_conv1<<<BB * PR, 256, 0, stream>>>(in_, w1, bn1_g, bn1_b, bn1_m, bn1_v, act);
  k_wb<<<2304, 256, 0, stream>>>(w2, bn2_g, bn2_v, Wb);
  k_conv2<<<256, 512, 0, stream>>>(act, Wb, in_, bn2_g, bn2_b, bn2_m, bn2_v, out);
}

// Round 7
// 105.953 us; speedup vs baseline: 1.5545x; 1.0364x over previous
//
#include <hip/hip_runtime.h>
#include <hip/hip_bf16.h>

#define BB 16
#define XY 64
#define CC 256
#define PR 66   // padded rows/cols (64 + halo)

typedef __attribute__((ext_vector_type(8)))  short short8;
typedef __attribute__((ext_vector_type(16))) float f32x16;
typedef __hip_bfloat16 bf16;

__device__ __forceinline__ void glds16(const void* g, void* l) {
  __builtin_amdgcn_global_load_lds(
      (const __attribute__((address_space(1))) void*)g,
      (__attribute__((address_space(3))) void*)l, 16, 0, 0);
}

// ---------------- Kernel 1: conv1 + BN1 + ReLU -> act[b][prow 66][kg 32][wp 66][8] bf16
__global__ __launch_bounds__(256) void k_conv1(
    const float* __restrict__ in,      // (B,64,64)
    const float* __restrict__ w1,      // (C,1,3,3)
    const float* __restrict__ g, const float* __restrict__ bbias,
    const float* __restrict__ m, const float* __restrict__ v,
    bf16* __restrict__ act)
{
  int blk = blockIdx.x;
  int b = blk / PR, prow = blk % PR;
  short8* base = (short8*)(act + (size_t)(b * PR + prow) * 32 * PR * 8);
  int tid = threadIdx.x;
  short8 z8 = {0, 0, 0, 0, 0, 0, 0, 0};
  if (prow == 0 || prow == PR - 1) {
    for (int i = tid; i < 32 * PR; i += 256) base[i] = z8;
    return;
  }
  __shared__ float inrow[3][PR];
  int h = prow - 1;
  for (int t = tid; t < 3 * PR; t += 256) {
    int r = t / PR, x = t % PR;
    int hr = h - 1 + r, wr = x - 1;
    inrow[r][x] = (hr >= 0 && hr < XY && wr >= 0 && wr < XY)
                      ? in[(b * XY + hr) * XY + wr] : 0.f;
  }
  __syncthreads();
  int cg = tid >> 3, w8 = tid & 7;
  float wr_[8][9], sc[8], tc[8];
#pragma unroll
  for (int u = 0; u < 8; ++u) {
    int c = cg * 8 + u;
#pragma unroll
    for (int t = 0; t < 9; ++t) wr_[u][t] = w1[c * 9 + t];
    float s = g[c] * rsqrtf(v[c] + 1e-5f);
    sc[u] = s; tc[u] = bbias[c] - m[c] * s;
  }
#pragma unroll
  for (int k = 0; k < 9; ++k) {
    int wp = w8 + 8 * k;
    if (wp < PR) {
      short8 outv = z8;
      if (wp != 0 && wp != PR - 1) {
        float o[8];
#pragma unroll
        for (int u = 0; u < 8; ++u) o[u] = 0.f;
#pragma unroll
        for (int dy = 0; dy < 3; ++dy) {
          float i0 = inrow[dy][wp - 1], i1 = inrow[dy][wp], i2 = inrow[dy][wp + 1];
#pragma unroll
          for (int u = 0; u < 8; ++u)
            o[u] += i0 * wr_[u][dy * 3] + i1 * wr_[u][dy * 3 + 1] + i2 * wr_[u][dy * 3 + 2];
        }
#pragma unroll
        for (int u = 0; u < 8; ++u) {
          bf16 hb = __float2bfloat16(fmaxf(fmaf(o[u], sc[u], tc[u]), 0.f));
          outv[u] = *(short*)&hb;
        }
      }
      base[cg * PR + wp] = outv;
    }
  }
}

// ---------------- Kernel 2: w2 -> Wb[(tap*8+cc)][kg 4][co 256][8] bf16, BN2-scaled
// ci = cc*32 + kg*8 + j; each (tap,cc) block = 16 KB contiguous.
__global__ __launch_bounds__(256) void k_wb(
    const float* __restrict__ w2,      // (co, ci, 3, 3)
    const float* __restrict__ g, const float* __restrict__ v,
    bf16* __restrict__ Wb)
{
  int e = blockIdx.x * 256 + threadIdx.x;   // < 589824
  int j   = e & 7;
  int co  = (e >> 3) & 255;
  int kg  = (e >> 11) & 3;
  int cc  = (e >> 13) & 7;
  int tap = e >> 16;
  int ci = cc * 32 + kg * 8 + j;
  float s = g[co] * rsqrtf(v[co] + 1e-5f);
  Wb[e] = __float2bfloat16(w2[((size_t)co * CC + ci) * 9 + tap] * s);
}

// ---------------- Kernel 3: conv2 via 4-wave 32x32x16 MFMA, 2 blocks/CU --------
// M=128 (2 out rows), N=256. 256 thr = 4 waves; wave (wm=wv>>1, wn=wv&1) owns
// out-row h0+wm x co[wn*128,+128): 2x4 tiles of 32x32, acc[2][4] f32x16.
// 72 iters (cc x tap), K=32. W 16KB blocks triple-buffered, staged 2 ahead,
// one vmcnt(4)+barrier per iter. A (4 rows x 4 kg x 66) restaged per cc.
__global__ __launch_bounds__(256, 2) void k_conv2(
    const bf16* __restrict__ act,      // (B,66,32,66,8)
    const bf16* __restrict__ Wb,       // (9,8,4,256,8)
    const float* __restrict__ in,      // (B,64,64) residual
    const float* __restrict__ g2, const float* __restrict__ b2,
    const float* __restrict__ m2, const float* __restrict__ v2,
    float* __restrict__ out)           // (B,4096,256)
{
  __shared__ alignas(16) bf16 Asm[1056 * 8];     // 16896 B  slot (r*4+kg)*66+wp
  __shared__ alignas(16) bf16 Wsm[3][1024 * 8];  // 49152 B  chunk kg*256+co
  __shared__ float inrow[2][64];

  int gg = blockIdx.x;                  // 512 blocks; XCD swizzle (512%8==0)
  int blk = (gg & 7) * 64 + (gg >> 3);
  int b = blk >> 5, h0 = (blk & 31) * 2;

  int tid = threadIdx.x;
  int lane = tid & 63, wv = tid >> 6;
  int wm = wv >> 1, wn = wv & 1;
  int l31 = lane & 31, lh = lane >> 5;

  f32x16 acc[2][4];
#pragma unroll
  for (int i = 0; i < 2; ++i)
#pragma unroll
    for (int j = 0; j < 4; ++j)
#pragma unroll
      for (int e = 0; e < 16; ++e) acc[i][j][e] = 0.f;

  if (tid < 128) inrow[tid >> 6][tid & 63] = in[(b * XY + h0 + (tid >> 6)) * XY + (tid & 63)];
  __syncthreads();   // clean vm/lgkm queues before counted region

  // wave wv stages padded row (h0+wv): 264 chunks (kg 0..3 x wp 0..65), 5 glds
  auto stageA = [&](int cc) {
    const char* srcbase = (const char*)act +
        (size_t)(((b * PR + h0 + wv) * 32 + cc * 4) * 66) * 16;
    char* dstbase = (char*)Asm + wv * (264 * 16);
#pragma unroll
    for (int k = 0; k < 4; ++k)
      glds16(srcbase + k * 1024 + lane * 16, dstbase + k * 1024);
    if (lane < 8)
      glds16(srcbase + 4096 + lane * 16, dstbase + 4096);
  };
  // 16 KB W block -> Wsm[sbuf]; 4 glds/wave
  auto stageW = [&](int wblk, int sbuf) {
    const char* src = (const char*)Wb + (size_t)wblk * 16384 + wv * 4096;
    char* dst = (char*)&Wsm[0][0] + sbuf * 16384 + wv * 4096;
#pragma unroll
    for (int k = 0; k < 4; ++k)
      glds16(src + k * 1024 + lane * 16, dst + k * 1024);
  };

  // ---- prologue: A(cc0) [5], W(it0)->buf0 [4], W(it1)->buf1 [4] ----
  stageA(0);
  stageW(0, 0);        // it0 = (tap0,cc0) -> wblk 0
  stageW(8, 1);        // it1 = (tap1,cc0) -> wblk 8
  asm volatile("s_waitcnt vmcnt(4)" ::: "memory");   // drain A+W0, keep W1
  __builtin_amdgcn_s_barrier();

  int it = 0, buf = 0;
#pragma unroll 1
  for (int cc = 0; cc < 8; ++cc) {
#pragma unroll 1
    for (int tap = 0; tap < 9; ++tap, ++it) {
      int dy = tap / 3, dx = tap - dy * 3;
      int sbuf = buf + 2; if (sbuf >= 3) sbuf -= 3;   // (it+2)%3
      int tap2 = tap + 2, cc2 = cc;
      if (tap2 >= 9) { tap2 -= 9; ++cc2; }
      int wblk2 = tap2 * 8 + cc2;
      bool doW = (it < 70);

      if (tap != 8 && doW) stageW(wblk2, sbuf);

      // ---- frag reads: A 4x b128, B 8x b128 (imm-offset from 2 bases) ----
      const bf16* wbuf = (const bf16*)((const char*)&Wsm[0][0] + buf * 16384);
      int abase = ((wm + dy) * 4 + lh) * 66 + l31 + dx;   // chunk idx
      int bbase = lh * 256 + wn * 128 + l31;              // chunk idx
      short8 a[2][2], bf_[2][4];
#pragma unroll
      for (int s = 0; s < 2; ++s)
#pragma unroll
        for (int mt = 0; mt < 2; ++mt)
          a[s][mt] = *(const short8*)(Asm + (size_t)(abase + s * 132 + mt * 32) * 8);
#pragma unroll
      for (int s = 0; s < 2; ++s)
#pragma unroll
        for (int nt = 0; nt < 4; ++nt)
          bf_[s][nt] = *(const short8*)(wbuf + (size_t)(bbase + s * 512 + nt * 32) * 8);

      if (tap == 8 && it < 71) {
        // A(cc) fully read into regs -> fence, then restage A and W
        asm volatile("s_waitcnt lgkmcnt(0)" ::: "memory");
        __builtin_amdgcn_s_barrier();
        stageA(cc + 1);
        stageW(wblk2, sbuf);
      }

      // ---- 16 MFMA (32x32x16): acc[mt][nt] += A[s][mt] * B[s][nt] ----
      __builtin_amdgcn_s_setprio(1);
#pragma unroll
      for (int s = 0; s < 2; ++s)
#pragma unroll
        for (int mt = 0; mt < 2; ++mt)
#pragma unroll
          for (int nt = 0; nt < 4; ++nt)
            acc[mt][nt] = __builtin_amdgcn_mfma_f32_32x32x16_bf16(
                a[s][mt], bf_[s][nt], acc[mt][nt], 0, 0, 0);
      __builtin_amdgcn_s_setprio(0);

      if (it >= 70) asm volatile("s_waitcnt vmcnt(0)" ::: "memory");
      else          asm volatile("s_waitcnt vmcnt(4)" ::: "memory");
      __builtin_amdgcn_s_barrier();
      buf = (buf == 2) ? 0 : buf + 1;
    }
  }

  // ---- epilogue: +bias2, ReLU, +input, ReLU ----
  // C/D (32x32): col = l31 (co), row = (e&3) + 8*(e>>2) + 4*lh  [m74/m101]
  float t2[4];
#pragma unroll
  for (int nt = 0; nt < 4; ++nt) {
    int co = wn * 128 + nt * 32 + l31;
    float s2 = g2[co] * rsqrtf(v2[co] + 1e-5f);
    t2[nt] = b2[co] - m2[co] * s2;
  }
#pragma unroll
  for (int mt = 0; mt < 2; ++mt) {
#pragma unroll
    for (int e = 0; e < 16; ++e) {
      int wp = mt * 32 + (e & 3) + 8 * (e >> 2) + 4 * lh;
      float iv = inrow[wm][wp];
      float* ob = out + ((size_t)((b * XY + h0 + wm) * XY + wp)) * CC + wn * 128 + l31;
#pragma unroll
      for (int nt = 0; nt < 4; ++nt) {
        float val = fmaxf(acc[mt][nt][e] + t2[nt], 0.f);
        ob[nt * 32] = fmaxf(iv + val, 0.f);
      }
    }
  }
}

extern "C" void kernel_launch(void* const* d_in, const int* in_sizes, int n_in,
                              void* d_out, int out_size, void* d_ws, size_t ws_size,
                              hipStream_t stream) {
  const float* in_   = (const float*)d_in[0];   // (16,64,64)
  const float* w1    = (const float*)d_in[3];   // (256,1,3,3)
  const float* w2    = (const float*)d_in[4];   // (256,256,3,3)
  const float* bn1_g = (const float*)d_in[5];
  const float* bn1_b = (const float*)d_in[6];
  const float* bn1_m = (const float*)d_in[7];
  const float* bn1_v = (const float*)d_in[8];
  const float* bn2_g = (const float*)d_in[9];
  const float* bn2_b = (const float*)d_in[10];
  const float* bn2_m = (const float*)d_in[11];
  const float* bn2_v = (const float*)d_in[12];
  float* out = (float*)d_out;

  bf16* act = (bf16*)d_ws;                         // (16,66,32,66,8) bf16 = 35.7 MB
  bf16* Wb  = act + (size_t)BB * PR * 32 * PR * 8; // (9,8,4,256,8) bf16 = 1.18 MB

  k_conv1<<<BB * PR, 256, 0, stream>>>(in_, w1, bn1_g, bn1_b, bn1_m, bn1_v, act);
  k_wb<<<2304, 256, 0, stream>>>(w2, bn2_g, bn2_v, Wb);
  k_conv2<<<512, 256, 0, stream>>>(act, Wb, in_, bn2_g, bn2_b, bn2_m, bn2_v, out);
}

// Round 8
// 104.868 us; speedup vs baseline: 1.5705x; 1.0104x over previous
//
#include <hip/hip_runtime.h>
#include <hip/hip_bf16.h>

#define BB 16
#define XY 64
#define CC 256
#define PR 66   // padded rows/cols (64 + halo)

typedef __attribute__((ext_vector_type(8)))  short short8;
typedef __attribute__((ext_vector_type(16))) float f32x16;
typedef __hip_bfloat16 bf16;

__device__ __forceinline__ void glds16(const void* g, void* l) {
  __builtin_amdgcn_global_load_lds(
      (const __attribute__((address_space(1))) void*)g,
      (__attribute__((address_space(3))) void*)l, 16, 0, 0);
}

// ---------------- Kernel 1: conv1 + BN1 + ReLU -> act[b][prow 66][kg 32][wp 66][8] bf16
__global__ __launch_bounds__(256) void k_conv1(
    const float* __restrict__ in,      // (B,64,64)
    const float* __restrict__ w1,      // (C,1,3,3)
    const float* __restrict__ g, const float* __restrict__ bbias,
    const float* __restrict__ m, const float* __restrict__ v,
    bf16* __restrict__ act)
{
  int blk = blockIdx.x;
  int b = blk / PR, prow = blk % PR;
  short8* base = (short8*)(act + (size_t)(b * PR + prow) * 32 * PR * 8);
  int tid = threadIdx.x;
  short8 z8 = {0, 0, 0, 0, 0, 0, 0, 0};
  if (prow == 0 || prow == PR - 1) {
    for (int i = tid; i < 32 * PR; i += 256) base[i] = z8;
    return;
  }
  __shared__ float inrow[3][PR];
  int h = prow - 1;
  for (int t = tid; t < 3 * PR; t += 256) {
    int r = t / PR, x = t % PR;
    int hr = h - 1 + r, wr = x - 1;
    inrow[r][x] = (hr >= 0 && hr < XY && wr >= 0 && wr < XY)
                      ? in[(b * XY + hr) * XY + wr] : 0.f;
  }
  __syncthreads();
  int cg = tid >> 3, w8 = tid & 7;
  float wr_[8][9], sc[8], tc[8];
#pragma unroll
  for (int u = 0; u < 8; ++u) {
    int c = cg * 8 + u;
#pragma unroll
    for (int t = 0; t < 9; ++t) wr_[u][t] = w1[c * 9 + t];
    float s = g[c] * rsqrtf(v[c] + 1e-5f);
    sc[u] = s; tc[u] = bbias[c] - m[c] * s;
  }
#pragma unroll
  for (int k = 0; k < 9; ++k) {
    int wp = w8 + 8 * k;
    if (wp < PR) {
      short8 outv = z8;
      if (wp != 0 && wp != PR - 1) {
        float o[8];
#pragma unroll
        for (int u = 0; u < 8; ++u) o[u] = 0.f;
#pragma unroll
        for (int dy = 0; dy < 3; ++dy) {
          float i0 = inrow[dy][wp - 1], i1 = inrow[dy][wp], i2 = inrow[dy][wp + 1];
#pragma unroll
          for (int u = 0; u < 8; ++u)
            o[u] += i0 * wr_[u][dy * 3] + i1 * wr_[u][dy * 3 + 1] + i2 * wr_[u][dy * 3 + 2];
        }
#pragma unroll
        for (int u = 0; u < 8; ++u) {
          bf16 hb = __float2bfloat16(fmaxf(fmaf(o[u], sc[u], tc[u]), 0.f));
          outv[u] = *(short*)&hb;
        }
      }
      base[cg * PR + wp] = outv;
    }
  }
}

// ---------------- Kernel 2: w2 -> Wb[(tap*8+cc)][kg 4][co 256][8] bf16, BN2-scaled
// ci = cc*32 + kg*8 + j; each (tap,cc) block = 16 KB contiguous.
__global__ __launch_bounds__(256) void k_wb(
    const float* __restrict__ w2,      // (co, ci, 3, 3)
    const float* __restrict__ g, const float* __restrict__ v,
    bf16* __restrict__ Wb)
{
  int e = blockIdx.x * 256 + threadIdx.x;   // < 589824
  int j   = e & 7;
  int co  = (e >> 3) & 255;
  int kg  = (e >> 11) & 3;
  int cc  = (e >> 13) & 7;
  int tap = e >> 16;
  int ci = cc * 32 + kg * 8 + j;
  float s = g[co] * rsqrtf(v[co] + 1e-5f);
  Wb[e] = __float2bfloat16(w2[((size_t)co * CC + ci) * 9 + tap] * s);
}

// ---------------- Kernel 3: conv2, 32x32x16 MFMA; W direct global->VGPR (L2-hot),
// A in LDS double-buffered. M=128 (2 rows), N=256, 4 waves, 2 blocks/CU.
// 72 iters (cc x tap), K=32. W software-pipelined 1 tap ahead in registers;
// barriers only at cc boundaries (9 per block instead of 144).
__global__ __launch_bounds__(256, 2) void k_conv2(
    const bf16* __restrict__ act,      // (B,66,32,66,8)
    const bf16* __restrict__ Wb,       // (9,8,4,256,8)
    const float* __restrict__ in,      // (B,64,64) residual
    const float* __restrict__ g2, const float* __restrict__ b2,
    const float* __restrict__ m2, const float* __restrict__ v2,
    float* __restrict__ out)           // (B,4096,256)
{
  __shared__ alignas(16) bf16 Asm[2][1056 * 8];  // 2 x 16896 B, slot (r*4+kg)*66+wp
  __shared__ float inrow[2][64];

  int gg = blockIdx.x;                  // 512 blocks; XCD swizzle (512%8==0)
  int blk = (gg & 7) * 64 + (gg >> 3);
  int b = blk >> 5, h0 = (blk & 31) * 2;

  int tid = threadIdx.x;
  int lane = tid & 63, wv = tid >> 6;
  int wm = wv >> 1, wnn = wv & 1;
  int l31 = lane & 31, lh = lane >> 5;

  f32x16 acc[2][4];
#pragma unroll
  for (int i = 0; i < 2; ++i)
#pragma unroll
    for (int j = 0; j < 4; ++j)
#pragma unroll
      for (int e = 0; e < 16; ++e) acc[i][j][e] = 0.f;

  if (tid < 128) inrow[tid >> 6][tid & 63] = in[(b * XY + h0 + (tid >> 6)) * XY + (tid & 63)];

  // wave wv stages padded row (h0+wv) of channel-chunk cn into Asm[cn&1]; 5 parts
  auto stageApart = [&](int cn, int part) {
    const char* srcbase = (const char*)act +
        (size_t)(((b * PR + h0 + wv) * 32 + cn * 4) * 66) * 16;
    char* dstbase = (char*)&Asm[cn & 1][0] + wv * (264 * 16);
    if (part < 4)
      glds16(srcbase + part * 1024 + lane * 16, dstbase + part * 1024);
    else if (lane < 8)
      glds16(srcbase + 4096 + lane * 16, dstbase + 4096);
  };

  // prologue: full A(cc=0) stage + preload W(it=0) fragments into regs
#pragma unroll
  for (int p = 0; p < 5; ++p) stageApart(0, p);

  int wfoff = lh * 256 + wnn * 128 + l31;     // chunk offset within a W block
  short8 wc[2][4];
  {
    const short8* ws0 = (const short8*)Wb;    // wblk 0 = (tap0, cc0)
#pragma unroll
    for (int s = 0; s < 2; ++s)
#pragma unroll
      for (int nt = 0; nt < 4; ++nt)
        wc[s][nt] = ws0[(s * 512) + wfoff + nt * 32];
  }
  __syncthreads();   // A(0) + inrow visible; drains everything once

#pragma unroll 1
  for (int cc = 0; cc < 8; ++cc) {
    const bf16* abuf = &Asm[cc & 1][0];
#pragma unroll 1
    for (int tap = 0; tap < 9; ++tap) {
      int it = cc * 9 + tap;
      // ---- issue next W-fragment loads (global, L2-hot; stay in flight over MFMA)
      int itn = (it < 71) ? it + 1 : 71;
      int ccn = itn / 9, tapn = itn - ccn * 9;
      const short8* wsn = (const short8*)(Wb + (size_t)(tapn * 8 + ccn) * 8192);
      short8 wn_[2][4];
#pragma unroll
      for (int s = 0; s < 2; ++s)
#pragma unroll
        for (int nt = 0; nt < 4; ++nt)
          wn_[s][nt] = wsn[(s * 512) + wfoff + nt * 32];

      // ---- interleaved A-stage for next cc (1 glds/wave/tap, taps 0..4) ----
      if (tap < 5 && cc < 7) stageApart(cc + 1, tap);

      // ---- A fragments from LDS ----
      int dy = tap / 3, dx = tap - dy * 3;
      int abase = ((wm + dy) * 4 + lh) * 66 + l31 + dx;
      short8 a[2][2];
#pragma unroll
      for (int s = 0; s < 2; ++s)
#pragma unroll
        for (int mt = 0; mt < 2; ++mt)
          a[s][mt] = *(const short8*)(abuf + (size_t)(abase + s * 132 + mt * 32) * 8);

      // ---- 16 MFMA (32x32x16) on current W regs ----
      __builtin_amdgcn_s_setprio(1);
#pragma unroll
      for (int s = 0; s < 2; ++s)
#pragma unroll
        for (int mt = 0; mt < 2; ++mt)
#pragma unroll
          for (int nt = 0; nt < 4; ++nt)
            acc[mt][nt] = __builtin_amdgcn_mfma_f32_32x32x16_bf16(
                a[s][mt], wn_[0][0] /*placeholder avoided*/ + 0 ? wc[s][nt] : wc[s][nt],
                acc[mt][nt], 0, 0, 0);
      __builtin_amdgcn_s_setprio(0);

      // ---- rotate W pipeline ----
#pragma unroll
      for (int s = 0; s < 2; ++s)
#pragma unroll
        for (int nt = 0; nt < 4; ++nt)
          wc[s][nt] = wn_[s][nt];
    }
    __syncthreads();   // A(cc+1) staged+visible; all waves done reading A(cc)
  }

  // ---- epilogue: +bias2, ReLU, +input, ReLU ----
  // C/D (32x32): col = l31 (co), row = (e&3) + 8*(e>>2) + 4*lh  [m74/m101]
  float t2[4];
#pragma unroll
  for (int nt = 0; nt < 4; ++nt) {
    int co = wnn * 128 + nt * 32 + l31;
    float s2 = g2[co] * rsqrtf(v2[co] + 1e-5f);
    t2[nt] = b2[co] - m2[co] * s2;
  }
#pragma unroll
  for (int mt = 0; mt < 2; ++mt) {
#pragma unroll
    for (int e = 0; e < 16; ++e) {
      int wp = mt * 32 + (e & 3) + 8 * (e >> 2) + 4 * lh;
      float iv = inrow[wm][wp];
      float* ob = out + ((size_t)((b * XY + h0 + wm) * XY + wp)) * CC + wnn * 128 + l31;
#pragma unroll
      for (int nt = 0; nt < 4; ++nt) {
        float val = fmaxf(acc[mt][nt][e] + t2[nt], 0.f);
        ob[nt * 32] = fmaxf(iv + val, 0.f);
      }
    }
  }
}

extern "C" void kernel_launch(void* const* d_in, const int* in_sizes, int n_in,
                              void* d_out, int out_size, void* d_ws, size_t ws_size,
                              hipStream_t stream) {
  const float* in_   = (const float*)d_in[0];   // (16,64,64)
  const float* w1    = (const float*)d_in[3];   // (256,1,3,3)
  const float* w2    = (const float*)d_in[4];   // (256,256,3,3)
  const float* bn1_g = (const float*)d_in[5];
  const float* bn1_b = (const float*)d_in[6];
  const float* bn1_m = (const float*)d_in[7];
  const float* bn1_v = (const float*)d_in[8];
  const float* bn2_g = (const float*)d_in[9];
  const float* bn2_b = (const float*)d_in[10];
  const float* bn2_m = (const float*)d_in[11];
  const float* bn2_v = (const float*)d_in[12];
  float* out = (float*)d_out;

  bf16* act = (bf16*)d_ws;                         // (16,66,32,66,8) bf16 = 35.7 MB
  bf16* Wb  = act + (size_t)BB * PR * 32 * PR * 8; // (9,8,4,256,8) bf16 = 1.18 MB

  k_conv1<<<BB * PR, 256, 0, stream>>>(in_, w1, bn1_g, bn1_b, bn1_m, bn1_v, act);
  k_wb<<<2304, 256, 0, stream>>>(w2, bn2_g, bn2_v, Wb);
  k_conv2<<<512, 256, 0, stream>>>(act, Wb, in_, bn2_g, bn2_b, bn2_m, bn2_v, out);
}

// Round 9
// 104.805 us; speedup vs baseline: 1.5715x; 1.0006x over previous
//
#include <hip/hip_runtime.h>
#include <hip/hip_bf16.h>

#define BB 16
#define XY 64
#define CC 256
#define PR 66   // padded rows/cols (64 + halo)

typedef __attribute__((ext_vector_type(8)))  short short8;
typedef __attribute__((ext_vector_type(16))) float f32x16;
typedef __hip_bfloat16 bf16;

__device__ __forceinline__ void glds16(const void* g, void* l) {
  __builtin_amdgcn_global_load_lds(
      (const __attribute__((address_space(1))) void*)g,
      (__attribute__((address_space(3))) void*)l, 16, 0, 0);
}

// ---------------- Kernel 1: conv1 + BN1 + ReLU -> act[b][prow 66][kg 32][wp 66][8] bf16
__global__ __launch_bounds__(256) void k_conv1(
    const float* __restrict__ in,      // (B,64,64)
    const float* __restrict__ w1,      // (C,1,3,3)
    const float* __restrict__ g, const float* __restrict__ bbias,
    const float* __restrict__ m, const float* __restrict__ v,
    bf16* __restrict__ act)
{
  int blk = blockIdx.x;
  int b = blk / PR, prow = blk % PR;
  short8* base = (short8*)(act + (size_t)(b * PR + prow) * 32 * PR * 8);
  int tid = threadIdx.x;
  short8 z8 = {0, 0, 0, 0, 0, 0, 0, 0};
  if (prow == 0 || prow == PR - 1) {
    for (int i = tid; i < 32 * PR; i += 256) base[i] = z8;
    return;
  }
  __shared__ float inrow[3][PR];
  int h = prow - 1;
  for (int t = tid; t < 3 * PR; t += 256) {
    int r = t / PR, x = t % PR;
    int hr = h - 1 + r, wr = x - 1;
    inrow[r][x] = (hr >= 0 && hr < XY && wr >= 0 && wr < XY)
                      ? in[(b * XY + hr) * XY + wr] : 0.f;
  }
  __syncthreads();
  int cg = tid >> 3, w8 = tid & 7;
  float wr_[8][9], sc[8], tc[8];
#pragma unroll
  for (int u = 0; u < 8; ++u) {
    int c = cg * 8 + u;
#pragma unroll
    for (int t = 0; t < 9; ++t) wr_[u][t] = w1[c * 9 + t];
    float s = g[c] * rsqrtf(v[c] + 1e-5f);
    sc[u] = s; tc[u] = bbias[c] - m[c] * s;
  }
#pragma unroll
  for (int k = 0; k < 9; ++k) {
    int wp = w8 + 8 * k;
    if (wp < PR) {
      short8 outv = z8;
      if (wp != 0 && wp != PR - 1) {
        float o[8];
#pragma unroll
        for (int u = 0; u < 8; ++u) o[u] = 0.f;
#pragma unroll
        for (int dy = 0; dy < 3; ++dy) {
          float i0 = inrow[dy][wp - 1], i1 = inrow[dy][wp], i2 = inrow[dy][wp + 1];
#pragma unroll
          for (int u = 0; u < 8; ++u)
            o[u] += i0 * wr_[u][dy * 3] + i1 * wr_[u][dy * 3 + 1] + i2 * wr_[u][dy * 3 + 2];
        }
#pragma unroll
        for (int u = 0; u < 8; ++u) {
          bf16 hb = __float2bfloat16(fmaxf(fmaf(o[u], sc[u], tc[u]), 0.f));
          outv[u] = *(short*)&hb;
        }
      }
      base[cg * PR + wp] = outv;
    }
  }
}

// ---------------- Kernel 2: w2 -> Wb[(tap*8+cc)][kg 4][co 256][8] bf16, BN2-scaled
// ci = cc*32 + kg*8 + j; each (tap,cc) block = 16 KB contiguous.
__global__ __launch_bounds__(256) void k_wb(
    const float* __restrict__ w2,      // (co, ci, 3, 3)
    const float* __restrict__ g, const float* __restrict__ v,
    bf16* __restrict__ Wb)
{
  int e = blockIdx.x * 256 + threadIdx.x;   // < 589824
  int j   = e & 7;
  int co  = (e >> 3) & 255;
  int kg  = (e >> 11) & 3;
  int cc  = (e >> 13) & 7;
  int tap = e >> 16;
  int ci = cc * 32 + kg * 8 + j;
  float s = g[co] * rsqrtf(v[co] + 1e-5f);
  Wb[e] = __float2bfloat16(w2[((size_t)co * CC + ci) * 9 + tap] * s);
}

// ---------------- Kernel 3: conv2, 32x32x16 MFMA; W direct global->VGPR (L2-hot),
// A in LDS double-buffered. M=128 (2 rows), N=256, 4 waves, 2 blocks/CU.
// 72 iters (cc x tap), K=32. W software-pipelined 1 iter ahead in registers
// (MFMA uses PREV-iter regs only -> no vmem wait before MFMA cluster).
__global__ __launch_bounds__(256, 2) void k_conv2(
    const bf16* __restrict__ act,      // (B,66,32,66,8)
    const bf16* __restrict__ Wb,       // (9,8,4,256,8)
    const float* __restrict__ in,      // (B,64,64) residual
    const float* __restrict__ g2, const float* __restrict__ b2,
    const float* __restrict__ m2, const float* __restrict__ v2,
    float* __restrict__ out)           // (B,4096,256)
{
  __shared__ alignas(16) bf16 Asm[2][1056 * 8];  // 2 x 16896 B, slot (r*4+kg)*66+wp
  __shared__ float inrow[2][64];

  int gg = blockIdx.x;                  // 512 blocks; XCD swizzle (512%8==0)
  int blk = (gg & 7) * 64 + (gg >> 3);
  int b = blk >> 5, h0 = (blk & 31) * 2;

  int tid = threadIdx.x;
  int lane = tid & 63, wv = tid >> 6;
  int wm = wv >> 1, wnn = wv & 1;
  int l31 = lane & 31, lh = lane >> 5;

  f32x16 acc[2][4];
#pragma unroll
  for (int i = 0; i < 2; ++i)
#pragma unroll
    for (int j = 0; j < 4; ++j)
#pragma unroll
      for (int e = 0; e < 16; ++e) acc[i][j][e] = 0.f;

  if (tid < 128) inrow[tid >> 6][tid & 63] = in[(b * XY + h0 + (tid >> 6)) * XY + (tid & 63)];

  // wave wv stages padded row (h0+wv) of channel-chunk cn into Asm[cn&1]; 5 parts
  auto stageApart = [&](int cn, int part) {
    const char* srcbase = (const char*)act +
        (size_t)(((b * PR + h0 + wv) * 32 + cn * 4) * 66) * 16;
    char* dstbase = (char*)&Asm[cn & 1][0] + wv * (264 * 16);
    if (part < 4)
      glds16(srcbase + part * 1024 + lane * 16, dstbase + part * 1024);
    else if (lane < 8)
      glds16(srcbase + 4096 + lane * 16, dstbase + 4096);
  };

  // prologue: full A(cc=0) stage + preload W(it=0) fragments into regs
#pragma unroll
  for (int p = 0; p < 5; ++p) stageApart(0, p);

  int wfoff = lh * 256 + wnn * 128 + l31;     // chunk offset within a W block
  short8 wc[2][4];
  {
    const short8* ws0 = (const short8*)Wb;    // wblk 0 = (tap0, cc0)
#pragma unroll
    for (int s = 0; s < 2; ++s)
#pragma unroll
      for (int nt = 0; nt < 4; ++nt)
        wc[s][nt] = ws0[(s * 512) + wfoff + nt * 32];
  }
  __syncthreads();   // A(0) + inrow visible; drains everything once

#pragma unroll 1
  for (int cc = 0; cc < 8; ++cc) {
    const bf16* abuf = &Asm[cc & 1][0];
#pragma unroll 3
    for (int tap = 0; tap < 9; ++tap) {
      int it = cc * 9 + tap;
      // ---- issue next-iter W-fragment loads (global, L2-hot; in flight over MFMA)
      int itn = (it < 71) ? it + 1 : 71;
      int ccn = itn / 9, tapn = itn - ccn * 9;
      const short8* wsn = (const short8*)(Wb + (size_t)(tapn * 8 + ccn) * 8192);
      short8 wn_[2][4];
#pragma unroll
      for (int s = 0; s < 2; ++s)
#pragma unroll
        for (int nt = 0; nt < 4; ++nt)
          wn_[s][nt] = wsn[(s * 512) + wfoff + nt * 32];

      // ---- interleaved A-stage for next cc (1 glds/wave/tap, taps 0..4) ----
      if (tap < 5 && cc < 7) stageApart(cc + 1, tap);

      // ---- A fragments from LDS ----
      int dy = tap / 3, dx = tap - dy * 3;
      int abase = ((wm + dy) * 4 + lh) * 66 + l31 + dx;
      short8 a[2][2];
#pragma unroll
      for (int s = 0; s < 2; ++s)
#pragma unroll
        for (int mt = 0; mt < 2; ++mt)
          a[s][mt] = *(const short8*)(abuf + (size_t)(abase + s * 132 + mt * 32) * 8);

      // ---- 16 MFMA (32x32x16) on PREV-iter W regs (no vmem dependency) ----
      __builtin_amdgcn_s_setprio(1);
#pragma unroll
      for (int s = 0; s < 2; ++s)
#pragma unroll
        for (int mt = 0; mt < 2; ++mt)
#pragma unroll
          for (int nt = 0; nt < 4; ++nt)
            acc[mt][nt] = __builtin_amdgcn_mfma_f32_32x32x16_bf16(
                a[s][mt], wc[s][nt], acc[mt][nt], 0, 0, 0);
      __builtin_amdgcn_s_setprio(0);

      // ---- rotate W pipeline (compiler renames across unroll-3 bodies) ----
#pragma unroll
      for (int s = 0; s < 2; ++s)
#pragma unroll
        for (int nt = 0; nt < 4; ++nt)
          wc[s][nt] = wn_[s][nt];
    }
    __syncthreads();   // A(cc+1) staged+visible; all waves done reading A(cc)
  }

  // ---- epilogue: +bias2, ReLU, +input, ReLU ----
  // C/D (32x32): col = l31 (co), row = (e&3) + 8*(e>>2) + 4*lh  [m74/m101]
  float t2[4];
#pragma unroll
  for (int nt = 0; nt < 4; ++nt) {
    int co = wnn * 128 + nt * 32 + l31;
    float s2 = g2[co] * rsqrtf(v2[co] + 1e-5f);
    t2[nt] = b2[co] - m2[co] * s2;
  }
#pragma unroll
  for (int mt = 0; mt < 2; ++mt) {
#pragma unroll
    for (int e = 0; e < 16; ++e) {
      int wp = mt * 32 + (e & 3) + 8 * (e >> 2) + 4 * lh;
      float iv = inrow[wm][wp];
      float* ob = out + ((size_t)((b * XY + h0 + wm) * XY + wp)) * CC + wnn * 128 + l31;
#pragma unroll
      for (int nt = 0; nt < 4; ++nt) {
        float val = fmaxf(acc[mt][nt][e] + t2[nt], 0.f);
        ob[nt * 32] = fmaxf(iv + val, 0.f);
      }
    }
  }
}

extern "C" void kernel_launch(void* const* d_in, const int* in_sizes, int n_in,
                              void* d_out, int out_size, void* d_ws, size_t ws_size,
                              hipStream_t stream) {
  const float* in_   = (const float*)d_in[0];   // (16,64,64)
  const float* w1    = (const float*)d_in[3];   // (256,1,3,3)
  const float* w2    = (const float*)d_in[4];   // (256,256,3,3)
  const float* bn1_g = (const float*)d_in[5];
  const float* bn1_b = (const float*)d_in[6];
  const float* bn1_m = (const float*)d_in[7];
  const float* bn1_v = (const float*)d_in[8];
  const float* bn2_g = (const float*)d_in[9];
  const float* bn2_b = (const float*)d_in[10];
  const float* bn2_m = (const float*)d_in[11];
  const float* bn2_v = (const float*)d_in[12];
  float* out = (float*)d_out;

  bf16* act = (bf16*)d_ws;                         // (16,66,32,66,8) bf16 = 35.7 MB
  bf16* Wb  = act + (size_t)BB * PR * 32 * PR * 8; // (9,8,4,256,8) bf16 = 1.18 MB

  k_conv1<<<BB * PR, 256, 0, stream>>>(in_, w1, bn1_g, bn1_b, bn1_m, bn1_v, act);
  k_wb<<<2304, 256, 0, stream>>>(w2, bn2_g, bn2_v, Wb);
  k_conv2<<<512, 256, 0, stream>>>(act, Wb, in_, bn2_g, bn2_b, bn2_m, bn2_v, out);
}